// Round 1
// baseline (694.283 us; speedup 1.0000x reference)
//
#include <hip/hip_runtime.h>
#include <hip/hip_bf16.h>
#include <stdint.h>

typedef __attribute__((ext_vector_type(8))) short short8;
typedef __attribute__((ext_vector_type(4))) float floatx4;

#define GLOAD_LDS16(gptr, lptr)                                                     \
  __builtin_amdgcn_global_load_lds(                                                 \
      (const __attribute__((address_space(1))) void*)(gptr),                        \
      (__attribute__((address_space(3))) void*)(lptr), 16, 0, 0)

// ---------------------------------------------------------------------------
// Kernel 1: W_eff[o][i] = Wscale * D4_CB[Qidxs[o][i/4]][i%4] + sum_r A[o][r]*B[r][i]
// grid (16 i-tiles of 256, 64 o-tiles of 64), block 256.
// ---------------------------------------------------------------------------
__global__ __launch_bounds__(256) void decode_weff(
    const int* __restrict__ Qidxs, const float* __restrict__ D4_CB,
    const float* __restrict__ Wscale_p, const float* __restrict__ A,
    const float* __restrict__ B, __hip_bfloat16* __restrict__ W_eff)
{
    __shared__ __align__(16) float As[64 * 64];   // A[oBase+oo][r]
    __shared__ __align__(16) float CB[256 * 4];
    const int t = threadIdx.x;
    const int oBase = blockIdx.y * 64;
    const int iBase = blockIdx.x * 256;

    // stage A tile (64x64 f32 = 1024 float4) and codebook (256 float4)
    const float4* A4 = (const float4*)(A + (long)oBase * 64);
    float4* As4 = (float4*)As;
#pragma unroll
    for (int u = 0; u < 4; ++u) As4[t + u * 256] = A4[t + u * 256];
    ((float4*)CB)[t] = ((const float4*)D4_CB)[t];
    __syncthreads();

    const float wscale = Wscale_p[0];
    const int i = iBase + t;
    // B column for this i (K=64)
    float bcol[64];
#pragma unroll
    for (int r = 0; r < 64; ++r) bcol[r] = B[r * 4096 + i];

    const int g = i >> 2;
    const int sub = i & 3;

    for (int oo = 0; oo < 64; ++oo) {
        const int o = oBase + oo;
        const float4* arow = (const float4*)&As[oo * 64];
        float acc = 0.f;
#pragma unroll
        for (int r4 = 0; r4 < 16; ++r4) {
            float4 a4 = arow[r4];
            acc += a4.x * bcol[4 * r4 + 0] + a4.y * bcol[4 * r4 + 1] +
                   a4.z * bcol[4 * r4 + 2] + a4.w * bcol[4 * r4 + 3];
        }
        const int q = Qidxs[(long)o * 1024 + g];
        const float w = wscale * CB[q * 4 + sub] + acc;
        W_eff[(long)o * 4096 + i] = __float2bfloat16(w);
    }
}

// ---------------------------------------------------------------------------
// Kernel 2: per row: x/scaleWH*SU -> FWHT(4096) -> *1/64 -> bf16
// one block per row (8192 rows), 256 threads, 16 KB LDS.
// ---------------------------------------------------------------------------
__global__ __launch_bounds__(256) void fwht_in_kernel(
    const float* __restrict__ x, const float* __restrict__ SU,
    const float* __restrict__ sWH, __hip_bfloat16* __restrict__ xh)
{
    __shared__ __align__(16) float row[4096];
    const int t = threadIdx.x;
    const long base = (long)blockIdx.x * 4096;
    const float4* xv = (const float4*)(x + base);
    const float4* suv = (const float4*)SU;
    const float4* swv = (const float4*)sWH;
#pragma unroll
    for (int u = 0; u < 4; ++u) {
        int idx = t + u * 256;
        float4 v = xv[idx], s = suv[idx], w = swv[idx];
        v.x = v.x / w.x * s.x;
        v.y = v.y / w.y * s.y;
        v.z = v.z / w.z * s.z;
        v.w = v.w / w.w * s.w;
        ((float4*)row)[idx] = v;
    }
    __syncthreads();
    for (int s = 0; s < 12; ++s) {
        const int h = 1 << s;
#pragma unroll
        for (int u = 0; u < 8; ++u) {
            int j = t + u * 256;                     // 2048 butterflies
            int i1 = ((j >> s) << (s + 1)) | (j & (h - 1));
            int i2 = i1 + h;
            float a = row[i1], b = row[i2];
            row[i1] = a + b;
            row[i2] = a - b;
        }
        __syncthreads();
    }
    ushort4* out = (ushort4*)(xh + base);
#pragma unroll
    for (int u = 0; u < 4; ++u) {
        int idx = t + u * 256;
        float4 v = ((float4*)row)[idx];
        ushort4 o;
        __hip_bfloat16 b0 = __float2bfloat16(v.x * 0.015625f);
        __hip_bfloat16 b1 = __float2bfloat16(v.y * 0.015625f);
        __hip_bfloat16 b2 = __float2bfloat16(v.z * 0.015625f);
        __hip_bfloat16 b3 = __float2bfloat16(v.w * 0.015625f);
        o.x = *(unsigned short*)&b0;
        o.y = *(unsigned short*)&b1;
        o.z = *(unsigned short*)&b2;
        o.w = *(unsigned short*)&b3;
        out[idx] = o;
    }
}

// ---------------------------------------------------------------------------
// Kernel 3: z[m][n] = sum_k xh[m][k] * W_eff[n][k]   (bf16 in, bf16 out)
// M=8192, N=4096, K=4096. 128x128 block tile, 4 waves of 64x64 (4x4 of
// 16x16x32 MFMA), BK=32, global_load_lds width-16 staging (m97 structure).
// grid (N/128=32, M/128=64), block 256.
// ---------------------------------------------------------------------------
__global__ __launch_bounds__(256) void gemm_bt(
    const __hip_bfloat16* __restrict__ xh,
    const __hip_bfloat16* __restrict__ wf,
    __hip_bfloat16* __restrict__ z)
{
    __shared__ __align__(16) __hip_bfloat16 lA[128 * 32];
    __shared__ __align__(16) __hip_bfloat16 lB[128 * 32];
    const int t = threadIdx.x;
    const int lane = t & 63;
    const int wv = t >> 6;             // wave 0..3
    const int wm = (wv >> 1) * 64;     // wave m-offset in tile
    const int wn = (wv & 1) * 64;      // wave n-offset in tile
    const long mBase = (long)blockIdx.y * 128;
    const long nBase = (long)blockIdx.x * 128;

    // staging: wave wv covers tile rows [wv*32, wv*32+32), two 16-row chunks.
    const int srow = wv * 32 + (lane >> 2);   // q=0 row
    const int skoff = (lane & 3) * 8;         // k offset in elements
    const __hip_bfloat16* gA = xh + (mBase + srow) * 4096 + skoff;
    const __hip_bfloat16* gB = wf + (nBase + srow) * 4096 + skoff;
    const long rstep = 16L * 4096;            // q=1 global row advance
    __hip_bfloat16* lA0 = &lA[(wv * 32) * 32];
    __hip_bfloat16* lA1 = &lA[(wv * 32 + 16) * 32];
    __hip_bfloat16* lB0 = &lB[(wv * 32) * 32];
    __hip_bfloat16* lB1 = &lB[(wv * 32 + 16) * 32];

    floatx4 acc[4][4] = {};
    const int fr = lane & 15;                 // fragment row/col within 16
    const int fq = (lane >> 4) * 8;           // fragment k offset

    for (int kt = 0; kt < 4096; kt += 32) {
        GLOAD_LDS16(gA + kt, lA0);
        GLOAD_LDS16(gA + kt + rstep, lA1);
        GLOAD_LDS16(gB + kt, lB0);
        GLOAD_LDS16(gB + kt + rstep, lB1);
        __syncthreads();

        short8 af[4], bfr[4];
#pragma unroll
        for (int i = 0; i < 4; ++i)
            af[i] = *(const short8*)&lA[(wm + i * 16 + fr) * 32 + fq];
#pragma unroll
        for (int j = 0; j < 4; ++j)
            bfr[j] = *(const short8*)&lB[(wn + j * 16 + fr) * 32 + fq];
#pragma unroll
        for (int i = 0; i < 4; ++i)
#pragma unroll
            for (int j = 0; j < 4; ++j)
                acc[i][j] = __builtin_amdgcn_mfma_f32_16x16x32_bf16(
                    af[i], bfr[j], acc[i][j], 0, 0, 0);
        __syncthreads();
    }

    // epilogue: C/D layout col=lane&15, row=(lane>>4)*4+reg  [m89/m91]
    const int q4 = (lane >> 4) * 4;
#pragma unroll
    for (int i = 0; i < 4; ++i)
#pragma unroll
        for (int j = 0; j < 4; ++j)
#pragma unroll
            for (int r = 0; r < 4; ++r) {
                const long rrow = mBase + wm + i * 16 + q4 + r;
                const long ccol = nBase + wn + j * 16 + fr;
                z[rrow * 4096 + ccol] = __float2bfloat16(acc[i][j][r]);
            }
}

// ---------------------------------------------------------------------------
// Kernel 4: per row: bf16 z -> FWHT(4096) -> *SV/64 -> fp32 out
// ---------------------------------------------------------------------------
__global__ __launch_bounds__(256) void fwht_out_kernel(
    const __hip_bfloat16* __restrict__ z, const float* __restrict__ SV,
    float* __restrict__ out)
{
    __shared__ __align__(16) float row[4096];
    const int t = threadIdx.x;
    const long base = (long)blockIdx.x * 4096;
    const ushort4* zv = (const ushort4*)(z + base);
#pragma unroll
    for (int u = 0; u < 4; ++u) {
        int idx = t + u * 256;
        ushort4 v = zv[idx];
        union { unsigned int u32; float f32; } c0, c1, c2, c3;
        c0.u32 = (unsigned int)v.x << 16;
        c1.u32 = (unsigned int)v.y << 16;
        c2.u32 = (unsigned int)v.z << 16;
        c3.u32 = (unsigned int)v.w << 16;
        float4 f = make_float4(c0.f32, c1.f32, c2.f32, c3.f32);
        ((float4*)row)[idx] = f;
    }
    __syncthreads();
    for (int s = 0; s < 12; ++s) {
        const int h = 1 << s;
#pragma unroll
        for (int u = 0; u < 8; ++u) {
            int j = t + u * 256;
            int i1 = ((j >> s) << (s + 1)) | (j & (h - 1));
            int i2 = i1 + h;
            float a = row[i1], b = row[i2];
            row[i1] = a + b;
            row[i2] = a - b;
        }
        __syncthreads();
    }
    const float4* svv = (const float4*)SV;
    float4* ov = (float4*)(out + base);
#pragma unroll
    for (int u = 0; u < 4; ++u) {
        int idx = t + u * 256;
        float4 v = ((float4*)row)[idx];
        float4 s = svv[idx];
        v.x = v.x * s.x * 0.015625f;
        v.y = v.y * s.y * 0.015625f;
        v.z = v.z * s.z * 0.015625f;
        v.w = v.w * s.w * 0.015625f;
        ov[idx] = v;
    }
}

// ---------------------------------------------------------------------------
extern "C" void kernel_launch(void* const* d_in, const int* in_sizes, int n_in,
                              void* d_out, int out_size, void* d_ws, size_t ws_size,
                              hipStream_t stream)
{
    const float* input  = (const float*)d_in[0];
    const int*   Qidxs  = (const int*)d_in[1];
    const float* D4_CB  = (const float*)d_in[2];
    const float* SU     = (const float*)d_in[3];
    const float* SV     = (const float*)d_in[4];
    const float* Wscale = (const float*)d_in[5];
    const float* A      = (const float*)d_in[6];
    const float* B      = (const float*)d_in[7];
    const float* sWH    = (const float*)d_in[8];
    float* out = (float*)d_out;

    char* ws = (char*)d_ws;
    __hip_bfloat16* weff = (__hip_bfloat16*)ws;                          // 32 MiB
    __hip_bfloat16* xh   = (__hip_bfloat16*)(ws + (32L << 20));          // 64 MiB
    __hip_bfloat16* zbuf = (__hip_bfloat16*)(ws + (32L << 20) + (64L << 20)); // 64 MiB

    decode_weff<<<dim3(16, 64), 256, 0, stream>>>(Qidxs, D4_CB, Wscale, A, B, weff);
    fwht_in_kernel<<<8192, 256, 0, stream>>>(input, SU, sWH, xh);
    gemm_bt<<<dim3(32, 64), 256, 0, stream>>>(xh, weff, zbuf);
    fwht_out_kernel<<<8192, 256, 0, stream>>>(zbuf, SV, out);
}

// Round 2
// 667.755 us; speedup vs baseline: 1.0397x; 1.0397x over previous
//
#include <hip/hip_runtime.h>
#include <hip/hip_bf16.h>
#include <stdint.h>

typedef __attribute__((ext_vector_type(8))) short short8;
typedef __attribute__((ext_vector_type(4))) float floatx4;

#define GLOAD_LDS16(gptr, lptr)                                                     \
  __builtin_amdgcn_global_load_lds(                                                 \
      (const __attribute__((address_space(1))) void*)(gptr),                        \
      (__attribute__((address_space(3))) void*)(lptr), 16, 0, 0)

__device__ inline void fwht16(float v[16]) {
#pragma unroll
    for (int s = 0; s < 4; ++s) {
        const int h = 1 << s;
#pragma unroll
        for (int k = 0; k < 16; k += 2 * h)
#pragma unroll
            for (int j = 0; j < h; ++j) {
                float a = v[k + j], b = v[k + j + h];
                v[k + j] = a + b;
                v[k + j + h] = a - b;
            }
    }
}

// ---------------------------------------------------------------------------
// Kernel 1: W_eff[o][i] = Wscale * D4_CB[Qidxs[o][i/4]][i%4] + sum_r A[o][r]*B[r][i]
// grid (16 i-tiles of 256, 64 o-tiles of 64), block 256.
// ---------------------------------------------------------------------------
__global__ __launch_bounds__(256) void decode_weff(
    const int* __restrict__ Qidxs, const float* __restrict__ D4_CB,
    const float* __restrict__ Wscale_p, const float* __restrict__ A,
    const float* __restrict__ B, __hip_bfloat16* __restrict__ W_eff)
{
    __shared__ __align__(16) float As[64 * 64];   // A[oBase+oo][r]
    __shared__ __align__(16) float CB[256 * 4];
    const int t = threadIdx.x;
    const int oBase = blockIdx.y * 64;
    const int iBase = blockIdx.x * 256;

    const float4* A4 = (const float4*)(A + (long)oBase * 64);
    float4* As4 = (float4*)As;
#pragma unroll
    for (int u = 0; u < 4; ++u) As4[t + u * 256] = A4[t + u * 256];
    ((float4*)CB)[t] = ((const float4*)D4_CB)[t];
    __syncthreads();

    const float wscale = Wscale_p[0];
    const int i = iBase + t;
    float bcol[64];
#pragma unroll
    for (int r = 0; r < 64; ++r) bcol[r] = B[r * 4096 + i];

    const int g = i >> 2;
    const int sub = i & 3;

    for (int oo = 0; oo < 64; ++oo) {
        const int o = oBase + oo;
        const float4* arow = (const float4*)&As[oo * 64];
        float acc = 0.f;
#pragma unroll
        for (int r4 = 0; r4 < 16; ++r4) {
            float4 a4 = arow[r4];
            acc += a4.x * bcol[4 * r4 + 0] + a4.y * bcol[4 * r4 + 1] +
                   a4.z * bcol[4 * r4 + 2] + a4.w * bcol[4 * r4 + 3];
        }
        const int q = Qidxs[(long)o * 1024 + g];
        const float w = wscale * CB[q * 4 + sub] + acc;
        W_eff[(long)o * 4096 + i] = __float2bfloat16(w);
    }
}

// ---------------------------------------------------------------------------
// Kernel 2: per row: x/scaleWH*SU -> FWHT(4096) -> *1/64 -> bf16
// Register FWHT16 x 3 phases (bits 8-11, 4-7, 0-3; stages commute).
// LDS padded pa(e)=e+(e>>4): phase transitions are ~2-way-conflict max.
// ---------------------------------------------------------------------------
__global__ __launch_bounds__(256) void fwht_in_kernel(
    const float* __restrict__ x, const float* __restrict__ SU,
    const float* __restrict__ sWH, __hip_bfloat16* __restrict__ xh)
{
    __shared__ float row[4096 + 256];
    const int t = threadIdx.x;
    const long base = (long)blockIdx.x * 4096;
    float v[16];

    // phase A: e = u*256 + t  (bits 8-11), coalesced global loads
#pragma unroll
    for (int u = 0; u < 16; ++u) {
        int e = u * 256 + t;
        v[u] = x[base + e] / sWH[e] * SU[e];
    }
    fwht16(v);
#pragma unroll
    for (int u = 0; u < 16; ++u) {
        int e = u * 256 + t;
        row[e + (e >> 4)] = v[u];   // pa = u*272 + t + (t>>4)
    }
    __syncthreads();

    // phase B: e = hi*256 + u*16 + lo  (bits 4-7); pa = hi*272 + u*17 + lo
    const int lo = t & 15, hi = t >> 4;
#pragma unroll
    for (int u = 0; u < 16; ++u) v[u] = row[hi * 272 + u * 17 + lo];
    fwht16(v);
#pragma unroll
    for (int u = 0; u < 16; ++u) row[hi * 272 + u * 17 + lo] = v[u];
    __syncthreads();

    // phase C: e = t*16 + u  (bits 0-3); pa = t*17 + u
#pragma unroll
    for (int u = 0; u < 16; ++u) v[u] = row[t * 17 + u];
    fwht16(v);

    short8 o0, o1;
#pragma unroll
    for (int u = 0; u < 8; ++u) {
        __hip_bfloat16 b = __float2bfloat16(v[u] * 0.015625f);
        o0[u] = *(short*)&b;
    }
#pragma unroll
    for (int u = 0; u < 8; ++u) {
        __hip_bfloat16 b = __float2bfloat16(v[8 + u] * 0.015625f);
        o1[u] = *(short*)&b;
    }
    *(short8*)(xh + base + t * 16) = o0;
    *(short8*)(xh + base + t * 16 + 8) = o1;
}

// ---------------------------------------------------------------------------
// Kernel 3: z[m][n] = sum_k xh[m][k] * W_eff[n][k]   (bf16 in, bf16 out)
// m97 structure + XOR chunk swizzle: LDS slot (row, p) holds global k-chunk
// c' = p ^ ((row&15)>>1 & 3) -> fragment ds_read_b128 is 2-way max.
// ---------------------------------------------------------------------------
__global__ __launch_bounds__(256) void gemm_bt(
    const __hip_bfloat16* __restrict__ xh,
    const __hip_bfloat16* __restrict__ wf,
    __hip_bfloat16* __restrict__ z)
{
    __shared__ __align__(16) __hip_bfloat16 lA[128 * 32];
    __shared__ __align__(16) __hip_bfloat16 lB[128 * 32];
    const int t = threadIdx.x;
    const int lane = t & 63;
    const int wv = t >> 6;
    const int wm = (wv >> 1) * 64;
    const int wn = (wv & 1) * 64;
    const long mBase = (long)blockIdx.y * 128;
    const long nBase = (long)blockIdx.x * 128;

    // staging: lane l -> LDS (row r=l>>2, chunk p=l&3); global chunk c' = p ^ ((r>>1)&3)
    const int srow = wv * 32 + (lane >> 2);
    const int skoff = (((lane & 3) ^ ((lane >> 3) & 3)) * 8);
    const __hip_bfloat16* gA = xh + (mBase + srow) * 4096 + skoff;
    const __hip_bfloat16* gB = wf + (nBase + srow) * 4096 + skoff;
    const long rstep = 16L * 4096;
    __hip_bfloat16* lA0 = &lA[(wv * 32) * 32];
    __hip_bfloat16* lA1 = &lA[(wv * 32 + 16) * 32];
    __hip_bfloat16* lB0 = &lB[(wv * 32) * 32];
    __hip_bfloat16* lB1 = &lB[(wv * 32 + 16) * 32];

    floatx4 acc[4][4] = {};
    const int fr = lane & 15;
    const int q = lane >> 4;                 // k-chunk 0..3
    const int fq = (q ^ ((fr >> 1) & 3)) * 8; // swizzled chunk offset (elements)

    for (int kt = 0; kt < 4096; kt += 32) {
        GLOAD_LDS16(gA + kt, lA0);
        GLOAD_LDS16(gA + kt + rstep, lA1);
        GLOAD_LDS16(gB + kt, lB0);
        GLOAD_LDS16(gB + kt + rstep, lB1);
        __syncthreads();

        short8 af[4], bfr[4];
#pragma unroll
        for (int i = 0; i < 4; ++i)
            af[i] = *(const short8*)&lA[(wm + i * 16 + fr) * 32 + fq];
#pragma unroll
        for (int j = 0; j < 4; ++j)
            bfr[j] = *(const short8*)&lB[(wn + j * 16 + fr) * 32 + fq];
#pragma unroll
        for (int i = 0; i < 4; ++i)
#pragma unroll
            for (int j = 0; j < 4; ++j)
                acc[i][j] = __builtin_amdgcn_mfma_f32_16x16x32_bf16(
                    af[i], bfr[j], acc[i][j], 0, 0, 0);
        __syncthreads();
    }

    const int q4 = (lane >> 4) * 4;
#pragma unroll
    for (int i = 0; i < 4; ++i)
#pragma unroll
        for (int j = 0; j < 4; ++j)
#pragma unroll
            for (int r = 0; r < 4; ++r) {
                const long rrow = mBase + wm + i * 16 + q4 + r;
                const long ccol = nBase + wn + j * 16 + fr;
                z[rrow * 4096 + ccol] = __float2bfloat16(acc[i][j][r]);
            }
}

// ---------------------------------------------------------------------------
// Kernel 4: per row: bf16 z -> FWHT(4096) -> *SV/64 -> fp32 out
// Same register-FWHT structure as kernel 2.
// ---------------------------------------------------------------------------
__global__ __launch_bounds__(256) void fwht_out_kernel(
    const __hip_bfloat16* __restrict__ z, const float* __restrict__ SV,
    float* __restrict__ out)
{
    __shared__ float row[4096 + 256];
    const int t = threadIdx.x;
    const long base = (long)blockIdx.x * 4096;
    float v[16];

#pragma unroll
    for (int u = 0; u < 16; ++u) {
        int e = u * 256 + t;
        v[u] = __bfloat162float(z[base + e]);
    }
    fwht16(v);
#pragma unroll
    for (int u = 0; u < 16; ++u) {
        int e = u * 256 + t;
        row[e + (e >> 4)] = v[u];
    }
    __syncthreads();

    const int lo = t & 15, hi = t >> 4;
#pragma unroll
    for (int u = 0; u < 16; ++u) v[u] = row[hi * 272 + u * 17 + lo];
    fwht16(v);
#pragma unroll
    for (int u = 0; u < 16; ++u) row[hi * 272 + u * 17 + lo] = v[u];
    __syncthreads();

#pragma unroll
    for (int u = 0; u < 16; ++u) v[u] = row[t * 17 + u];
    fwht16(v);

    const float4* svv = (const float4*)(SV + t * 16);
    float4* ov = (float4*)(out + base + t * 16);
#pragma unroll
    for (int c = 0; c < 4; ++c) {
        float4 s = svv[c];
        float4 f;
        f.x = v[4 * c + 0] * s.x * 0.015625f;
        f.y = v[4 * c + 1] * s.y * 0.015625f;
        f.z = v[4 * c + 2] * s.z * 0.015625f;
        f.w = v[4 * c + 3] * s.w * 0.015625f;
        ov[c] = f;
    }
}

// ---------------------------------------------------------------------------
extern "C" void kernel_launch(void* const* d_in, const int* in_sizes, int n_in,
                              void* d_out, int out_size, void* d_ws, size_t ws_size,
                              hipStream_t stream)
{
    const float* input  = (const float*)d_in[0];
    const int*   Qidxs  = (const int*)d_in[1];
    const float* D4_CB  = (const float*)d_in[2];
    const float* SU     = (const float*)d_in[3];
    const float* SV     = (const float*)d_in[4];
    const float* Wscale = (const float*)d_in[5];
    const float* A      = (const float*)d_in[6];
    const float* B      = (const float*)d_in[7];
    const float* sWH    = (const float*)d_in[8];
    float* out = (float*)d_out;

    char* ws = (char*)d_ws;
    __hip_bfloat16* weff = (__hip_bfloat16*)ws;                               // 32 MiB
    __hip_bfloat16* xh   = (__hip_bfloat16*)(ws + (32L << 20));               // 64 MiB
    __hip_bfloat16* zbuf = (__hip_bfloat16*)(ws + (32L << 20) + (64L << 20)); // 64 MiB

    decode_weff<<<dim3(16, 64), 256, 0, stream>>>(Qidxs, D4_CB, Wscale, A, B, weff);
    fwht_in_kernel<<<8192, 256, 0, stream>>>(input, SU, sWH, xh);
    gemm_bt<<<dim3(32, 64), 256, 0, stream>>>(xh, weff, zbuf);
    fwht_out_kernel<<<8192, 256, 0, stream>>>(zbuf, SV, out);
}